// Round 1
// baseline (1058.566 us; speedup 1.0000x reference)
//
#include <hip/hip_runtime.h>
#include <math.h>

#define HID 128
#define G3  384   // 3*HID
#define BATCH 256
#define SEQ 512

// ---------------------------------------------------------------------------
// Kernel 1: fold the Linear layer into the input-hidden GRU weights.
//   Wc[g][d] = sum_e W_ih[g][e] * lin_W[e][d]        (384 x 128)
//   bc[g]    = sum_e W_ih[g][e] * lin_b[e] + b_ih[g] (384)
// Then gx[s,b,g] = dot(Wc[g,:], X[s,b,:]) + bc[g] exactly equals
// (X @ lin_W^T + lin_b) @ W_ih^T + b_ih.
// ---------------------------------------------------------------------------
__global__ void fold_kernel(const float* __restrict__ lin_W,
                            const float* __restrict__ lin_b,
                            const float* __restrict__ W_ih,
                            const float* __restrict__ b_ih,
                            float* __restrict__ Wc,
                            float* __restrict__ bc) {
    const int g = blockIdx.x;   // 0..383
    const int d = threadIdx.x;  // 0..127
    float acc = 0.f;
    for (int e = 0; e < HID; ++e) {
        acc += W_ih[g * HID + e] * lin_W[e * HID + d];
    }
    Wc[g * HID + d] = acc;
    if (d == 0) {
        float b = 0.f;
        for (int e = 0; e < HID; ++e) b += W_ih[g * HID + e] * lin_b[e];
        bc[g] = b + b_ih[g];
    }
}

// ---------------------------------------------------------------------------
// Kernel 2: full GRU scan. One block per batch element (256 blocks = 1/CU).
// 768 threads: thread t handles output row (t>>1) in [0,384) and K-half
// (t&1). Weights for both Wc and W_hh are held in registers (64 fp32 each).
// h and the staged x row live in LDS. 512 sequential steps inside the block.
// ---------------------------------------------------------------------------
__global__ __launch_bounds__(768, 3)
void gru_scan_kernel(const float* __restrict__ X,
                     const float* __restrict__ h0,
                     const float* __restrict__ W_hh,
                     const float* __restrict__ b_hh,
                     const float* __restrict__ Wc,
                     const float* __restrict__ bc,
                     float* __restrict__ out) {
    const int b    = blockIdx.x;    // batch index
    const int t    = threadIdx.x;   // 0..767
    const int row  = t >> 1;        // 0..383 (gate row)
    const int half = t & 1;         // K-half: 0 -> k[0..63], 1 -> k[64..127]

    __shared__ float xs[HID];
    __shared__ float hl[HID];
    __shared__ float gxs[G3];
    __shared__ float ghs[G3];

    // ---- load per-thread weight slices into registers -------------------
    float wc[64], wh[64];
    {
        const float4* wcp = reinterpret_cast<const float4*>(Wc   + row * HID + half * 64);
        const float4* whp = reinterpret_cast<const float4*>(W_hh + row * HID + half * 64);
        #pragma unroll
        for (int j = 0; j < 16; ++j) {
            float4 a = wcp[j];
            wc[4*j+0] = a.x; wc[4*j+1] = a.y; wc[4*j+2] = a.z; wc[4*j+3] = a.w;
            float4 c = whp[j];
            wh[4*j+0] = c.x; wh[4*j+1] = c.y; wh[4*j+2] = c.z; wh[4*j+3] = c.w;
        }
    }
    const float biasx = bc[row];    // used by even (half==0) lanes only
    const float biash = b_hh[row];

    if (t < HID) hl[t] = h0[b * HID + t];
    // (xs is staged inside the loop; barrier there covers hl too)

    for (int s = 0; s < SEQ; ++s) {
        // stage x[s, b, :] into LDS (coalesced 512B)
        if (t < HID) xs[t] = X[((size_t)s * BATCH + b) * HID + t];
        __syncthreads();   // xs (and on s==0, hl) visible to all

        // ---- dual dot products: gx partial and gh partial ----------------
        float ax = 0.f, ah = 0.f;
        const float4* x4 = reinterpret_cast<const float4*>(xs) + half * 16;
        const float4* h4 = reinterpret_cast<const float4*>(hl) + half * 16;
        #pragma unroll
        for (int j = 0; j < 16; ++j) {
            float4 xv = x4[j];
            float4 hv = h4[j];
            ax += wc[4*j+0]*xv.x + wc[4*j+1]*xv.y + wc[4*j+2]*xv.z + wc[4*j+3]*xv.w;
            ah += wh[4*j+0]*hv.x + wh[4*j+1]*hv.y + wh[4*j+2]*hv.z + wh[4*j+3]*hv.w;
        }
        // reduce the two K-halves (lanes t and t^1 share a row)
        ax += __shfl_xor(ax, 1);
        ah += __shfl_xor(ah, 1);
        if (half == 0) {
            gxs[row] = ax + biasx;
            ghs[row] = ah + biash;
        }
        __syncthreads();   // gate pre-activations visible; hl reads done

        // ---- gates + state update (threads 0..127) -----------------------
        if (t < HID) {
            const int i = t;
            float r = 1.f / (1.f + __expf(-(gxs[i]       + ghs[i])));
            float z = 1.f / (1.f + __expf(-(gxs[HID+i]   + ghs[HID+i])));
            float n = tanhf(gxs[2*HID+i] + r * ghs[2*HID+i]);
            float hn = (1.f - z) * n + z * hl[i];
            hl[i] = hn;
            out[((size_t)s * BATCH + b) * HID + i] = hn;
        }
        __syncthreads();   // hl update visible before next step's dots
    }
}

// ---------------------------------------------------------------------------
extern "C" void kernel_launch(void* const* d_in, const int* in_sizes, int n_in,
                              void* d_out, int out_size, void* d_ws, size_t ws_size,
                              hipStream_t stream) {
    const float* X     = (const float*)d_in[0];  // (512, 256, 128)
    const float* h0    = (const float*)d_in[1];  // (1, 256, 128)
    const float* lin_W = (const float*)d_in[2];  // (128, 128)
    const float* lin_b = (const float*)d_in[3];  // (128)
    const float* W_ih  = (const float*)d_in[4];  // (384, 128)
    const float* W_hh  = (const float*)d_in[5];  // (384, 128)
    const float* b_ih  = (const float*)d_in[6];  // (384)
    const float* b_hh  = (const float*)d_in[7];  // (384)
    float* out = (float*)d_out;                  // (512, 256, 128)

    float* Wc = (float*)d_ws;                    // 384*128 floats
    float* bc = Wc + G3 * HID;                   // 384 floats

    fold_kernel<<<G3, HID, 0, stream>>>(lin_W, lin_b, W_ih, b_ih, Wc, bc);
    gru_scan_kernel<<<BATCH, 768, 0, stream>>>(X, h0, W_hh, b_hh, Wc, bc, out);
}

// Round 2
// 520.265 us; speedup vs baseline: 2.0347x; 2.0347x over previous
//
#include <hip/hip_runtime.h>
#include <math.h>

#define HID 128
#define G3  384
#define BATCH 256
#define SEQ 512
#define NB 16            // batch tile per block
#define NBLK (BATCH/NB)  // 16 blocks

typedef __bf16 bf16x8 __attribute__((ext_vector_type(8)));
typedef __bf16 bf16x4 __attribute__((ext_vector_type(4)));
typedef float  f32x4  __attribute__((ext_vector_type(4)));

#define LOG2E 1.44269504088896f

__device__ __forceinline__ float sigm(float x) {
    return __builtin_amdgcn_rcpf(1.f + __builtin_amdgcn_exp2f(-LOG2E * x));
}
__device__ __forceinline__ float tanh_fast(float x) {
    // tanh(x) = 2/(1+exp(-2x)) - 1  (saturates correctly at +-1)
    float e = __builtin_amdgcn_exp2f(-2.f * LOG2E * x);
    return __builtin_amdgcn_rcpf(1.f + e) * 2.f - 1.f;
}
__device__ __forceinline__ f32x4 mfma16(bf16x8 a, bf16x8 b, f32x4 c) {
    return __builtin_amdgcn_mfma_f32_16x16x32_bf16(a, b, c, 0, 0, 0);
}
__device__ __forceinline__ bf16x8 cvt8(float4 a, float4 b) {
    bf16x8 f;
    f[0] = (__bf16)a.x; f[1] = (__bf16)a.y; f[2] = (__bf16)a.z; f[3] = (__bf16)a.w;
    f[4] = (__bf16)b.x; f[5] = (__bf16)b.y; f[6] = (__bf16)b.z; f[7] = (__bf16)b.w;
    return f;
}

// ---------------------------------------------------------------------------
// Kernel 1: fold Linear into GRU input-hidden weights.
//   Wc[g][d]  = sum_e W_ih[g][e] * lin_W[e][d]            (384 x 128, f32)
//   bcA[g]    = sum_e W_ih[g][e] * lin_b[e] + b_ih[g]     (384, f32)
// ---------------------------------------------------------------------------
__global__ void fold_kernel(const float* __restrict__ lin_W,
                            const float* __restrict__ lin_b,
                            const float* __restrict__ W_ih,
                            const float* __restrict__ b_ih,
                            float* __restrict__ Wc,
                            float* __restrict__ bcA) {
    const int g = blockIdx.x;
    const int d = threadIdx.x;
    float acc = 0.f;
    for (int e = 0; e < HID; ++e) acc += W_ih[g * HID + e] * lin_W[e * HID + d];
    Wc[g * HID + d] = acc;
    if (d == 0) {
        float b = 0.f;
        for (int e = 0; e < HID; ++e) b += W_ih[g * HID + e] * lin_b[e];
        bcA[g] = b + b_ih[g];
    }
}

// ---------------------------------------------------------------------------
// Kernel 2: MFMA GRU scan. 16 blocks x 256 threads (4 waves).
// Block owns batch tile [bb, bb+16). Wave w owns 16-row tiles {w, w+4} of
// each gate (r rows T*16.., z rows 128+T*16.., n rows 256+T*16..).
// A-frags (bf16 W_hh and Wc) resident in VGPRs, pinned. h and x tiles live
// in XOR-swizzled LDS ([b][k] bf16, 256B rows, byte ^= (b&7)<<4).
// ---------------------------------------------------------------------------
__global__ __launch_bounds__(256, 1)
void gru_scan_mfma(const float* __restrict__ X,
                   const float* __restrict__ h0,
                   const float* __restrict__ W_hh,
                   const float* __restrict__ b_hh,
                   const float* __restrict__ Wc,
                   const float* __restrict__ bcA,
                   float* __restrict__ out) {
    const int t   = threadIdx.x;
    const int w   = t >> 6;
    const int l   = t & 63;
    const int col = l & 15;   // batch within tile (MFMA n / C col)
    const int lr  = l >> 4;   // 0..3 (k-group for A/B, row-group for C)
    const int bb  = blockIdx.x * NB;

    __shared__ __align__(16) unsigned char lds[12288];
    unsigned char* hbuf  = lds;           // 4 KB: h  [16][128] bf16 swizzled
    unsigned char* xbuf0 = lds + 4096;    // 4 KB: x double-buffer 0
    unsigned char* xbuf1 = lds + 8192;    // 4 KB: x double-buffer 1

    auto SW = [](int b, int off) { return b * 256 + (off ^ ((b & 7) << 4)); };

    const int T[2] = {w, w + 4};

    // ---- resident A-fragments: aW = W_hh, aC = Wc; [tile][gate][ktile] ----
    bf16x8 aW[2][3][4], aC[2][3][4];
    #pragma unroll
    for (int i = 0; i < 2; ++i)
        #pragma unroll
        for (int g3 = 0; g3 < 3; ++g3)
            #pragma unroll
            for (int kt = 0; kt < 4; ++kt) {
                const int row = g3 * HID + T[i] * 16 + col;
                const float* pw = W_hh + row * HID + kt * 32 + lr * 8;
                const float* pc = Wc   + row * HID + kt * 32 + lr * 8;
                float4 u = *(const float4*)pw, v = *(const float4*)(pw + 4);
                aW[i][g3][kt] = cvt8(u, v);
                u = *(const float4*)pc; v = *(const float4*)(pc + 4);
                aC[i][g3][kt] = cvt8(u, v);
            }
    #pragma unroll
    for (int i = 0; i < 2; ++i)
        #pragma unroll
        for (int g3 = 0; g3 < 3; ++g3)
            #pragma unroll
            for (int kt = 0; kt < 4; ++kt) {
                asm volatile("" : "+v"(aW[i][g3][kt]));
                asm volatile("" : "+v"(aC[i][g3][kt]));
            }

    // ---- biases per lane ------------------------------------------------
    float brz_r[2][4], brz_z[2][4], bnx[2][4], bnh[2][4];
    #pragma unroll
    for (int i = 0; i < 2; ++i)
        #pragma unroll
        for (int q = 0; q < 4; ++q) {
            const int g = T[i] * 16 + lr * 4 + q;
            brz_r[i][q] = bcA[g] + b_hh[g];
            brz_z[i][q] = bcA[HID + g] + b_hh[HID + g];
            bnx[i][q]   = bcA[2 * HID + g];
            bnh[i][q]   = b_hh[2 * HID + g];
        }

    // ---- h_old in registers (rows this lane owns) -----------------------
    f32x4 hold[2];
    #pragma unroll
    for (int i = 0; i < 2; ++i)
        hold[i] = *(const f32x4*)(h0 + (size_t)(bb + col) * HID + T[i] * 16 + lr * 4);

    // ---- stage h0 and x[0] into LDS; prefetch x[1] to regs --------------
    const int sb = t >> 4, sk = (t & 15) * 8;  // staging thread mapping
    float4 xpA0, xpA1, xpB0, xpB1;
    {
        const float* ph = h0 + (size_t)(bb + sb) * HID + sk;
        *(bf16x8*)(hbuf + SW(sb, sk * 2)) =
            cvt8(*(const float4*)ph, *(const float4*)(ph + 4));
        const float* px = X + ((size_t)0 * BATCH + bb + sb) * HID + sk;
        *(bf16x8*)(xbuf0 + SW(sb, sk * 2)) =
            cvt8(*(const float4*)px, *(const float4*)(px + 4));
        const float* px1 = X + ((size_t)1 * BATCH + bb + sb) * HID + sk;
        xpA0 = *(const float4*)px1; xpA1 = *(const float4*)(px1 + 4);
    }
    __syncthreads();

    const f32x4 vzero = {0.f, 0.f, 0.f, 0.f};

    auto STEP = [&](int s, unsigned char* xcur, unsigned char* xnxt,
                    float4& xc0, float4& xc1, float4& xn0, float4& xn1) {
        // B-fragments from LDS (shared across all row tiles)
        bf16x8 Bh[4], Bx[4];
        #pragma unroll
        for (int kt = 0; kt < 4; ++kt) {
            Bh[kt] = *(const bf16x8*)(hbuf + SW(col, kt * 64 + lr * 16));
            Bx[kt] = *(const bf16x8*)(xcur + SW(col, kt * 64 + lr * 16));
        }
        // prefetch x[s+2] (clamped; redundant loads at tail are harmless)
        {
            int sp = s + 2; if (sp > SEQ - 1) sp = SEQ - 1;
            const float* px = X + ((size_t)sp * BATCH + bb + sb) * HID + sk;
            xn0 = *(const float4*)px; xn1 = *(const float4*)(px + 4);
        }
        // MFMA phase: 48 per wave
        f32x4 accr[2], accz[2], accnh[2], accnx[2];
        #pragma unroll
        for (int i = 0; i < 2; ++i) { accr[i] = vzero; accz[i] = vzero; accnh[i] = vzero; accnx[i] = vzero; }
        #pragma unroll
        for (int i = 0; i < 2; ++i)
            #pragma unroll
            for (int kt = 0; kt < 4; ++kt) {
                accr[i]  = mfma16(aW[i][0][kt], Bh[kt], accr[i]);
                accr[i]  = mfma16(aC[i][0][kt], Bx[kt], accr[i]);
                accz[i]  = mfma16(aW[i][1][kt], Bh[kt], accz[i]);
                accz[i]  = mfma16(aC[i][1][kt], Bx[kt], accz[i]);
                accnh[i] = mfma16(aW[i][2][kt], Bh[kt], accnh[i]);
                accnx[i] = mfma16(aC[i][2][kt], Bx[kt], accnx[i]);
            }
        __syncthreads();   // all LDS reads of h/x done; safe to overwrite

        // stage x[s+1] (loaded last step) into the other x buffer
        *(bf16x8*)(xnxt + SW(sb, sk * 2)) = cvt8(xc0, xc1);

        // gate math (fp32, in registers) + h_new writeback
        #pragma unroll
        for (int i = 0; i < 2; ++i) {
            f32x4 hnew;
            #pragma unroll
            for (int q = 0; q < 4; ++q) {
                float r = sigm(accr[i][q] + brz_r[i][q]);
                float z = sigm(accz[i][q] + brz_z[i][q]);
                float n = tanh_fast(accnx[i][q] + bnx[i][q] +
                                    r * (accnh[i][q] + bnh[i][q]));
                hnew[q] = n + z * (hold[i][q] - n);
            }
            hold[i] = hnew;
            bf16x4 hb;
            hb[0] = (__bf16)hnew[0]; hb[1] = (__bf16)hnew[1];
            hb[2] = (__bf16)hnew[2]; hb[3] = (__bf16)hnew[3];
            *(bf16x4*)(hbuf + SW(col, (T[i] * 16 + lr * 4) * 2)) = hb;
            float4 o; o.x = hnew[0]; o.y = hnew[1]; o.z = hnew[2]; o.w = hnew[3];
            *(float4*)(out + ((size_t)s * BATCH + bb + col) * HID + T[i] * 16 + lr * 4) = o;
        }
        __syncthreads();   // h/x writes visible before next step's reads
    };

    for (int s0 = 0; s0 < SEQ; s0 += 2) {
        STEP(s0,     xbuf0, xbuf1, xpA0, xpA1, xpB0, xpB1);
        STEP(s0 + 1, xbuf1, xbuf0, xpB0, xpB1, xpA0, xpA1);
    }
}

// ---------------------------------------------------------------------------
extern "C" void kernel_launch(void* const* d_in, const int* in_sizes, int n_in,
                              void* d_out, int out_size, void* d_ws, size_t ws_size,
                              hipStream_t stream) {
    const float* X     = (const float*)d_in[0];
    const float* h0    = (const float*)d_in[1];
    const float* lin_W = (const float*)d_in[2];
    const float* lin_b = (const float*)d_in[3];
    const float* W_ih  = (const float*)d_in[4];
    const float* W_hh  = (const float*)d_in[5];
    const float* b_ih  = (const float*)d_in[6];
    const float* b_hh  = (const float*)d_in[7];
    float* out = (float*)d_out;

    float* Wc  = (float*)d_ws;          // 384*128 f32
    float* bcA = Wc + G3 * HID;         // 384 f32

    fold_kernel<<<G3, HID, 0, stream>>>(lin_W, lin_b, W_ih, b_ih, Wc, bcA);
    gru_scan_mfma<<<NBLK, 256, 0, stream>>>(X, h0, W_hh, b_hh, Wc, bcA, out);
}